// Round 1
// baseline (2047.006 us; speedup 1.0000x reference)
//
#include <hip/hip_runtime.h>

typedef short short8 __attribute__((ext_vector_type(8)));
typedef float f32x4 __attribute__((ext_vector_type(4)));

#define NWIN 2304
#define CP 520   // padded row (ushorts) for [64][512] tiles
#define LP 72    // padded row (ushorts) for [64][64] tiles
#define SMEM_BYTES 118272

static __device__ __forceinline__ unsigned short f2bf(float f) {
  unsigned int u = __float_as_uint(f);
  u += 0x7FFFu + ((u >> 16) & 1u);   // RNE
  return (unsigned short)(u >> 16);
}
static __device__ __forceinline__ float bf2f(unsigned short s) {
  return __uint_as_float(((unsigned int)s) << 16);
}
static __device__ __forceinline__ f32x4 mfma16(short8 a, short8 b, f32x4 c) {
  return __builtin_amdgcn_mfma_f32_16x16x32_bf16(a, b, c, 0, 0, 0);
}
static __device__ __forceinline__ short8 lds8(const unsigned short* p) {
  return *reinterpret_cast<const short8*>(p);
}

// ---- weight prep: in[K][N] f32  ->  out[N][K] bf16 ----
__global__ void transpose_cvt_kernel(const float* __restrict__ in,
                                     unsigned short* __restrict__ out,
                                     int K, int N) {
  __shared__ float tile[32][33];
  int bn = blockIdx.x * 32, bk = blockIdx.y * 32;
  int tx = threadIdx.x & 31, ty = threadIdx.x >> 5;  // 256 thr: 32 x 8
#pragma unroll
  for (int r = 0; r < 32; r += 8)
    tile[ty + r][tx] = in[(size_t)(bk + ty + r) * N + bn + tx];
  __syncthreads();
#pragma unroll
  for (int r = 0; r < 32; r += 8)
    out[(size_t)(bn + ty + r) * K + bk + tx] = f2bf(tile[tx][ty + r]);
}

__global__ __launch_bounds__(512, 2)
void swin_fused(const float* __restrict__ x,
                const unsigned short* __restrict__ WqkvT,  // [1536][512] bf16
                const float* __restrict__ bqkv,
                const unsigned short* __restrict__ WoT,    // [512][512]
                const float* __restrict__ bo,
                const float* __restrict__ g1, const float* __restrict__ beta1,
                const unsigned short* __restrict__ W1T,    // [512][512]
                const float* __restrict__ bf1,
                const unsigned short* __restrict__ W2T,    // [512][512]
                const float* __restrict__ bf2,
                const float* __restrict__ g2, const float* __restrict__ beta2,
                float* __restrict__ out) {
  extern __shared__ unsigned char smem[];
  unsigned short* sT  = (unsigned short*)smem;               // [64][CP] t / x1
  unsigned short* sQ  = (unsigned short*)(smem + 66560);     // [64][LP]
  unsigned short* sK  = sQ + 64 * LP;
  unsigned short* sVt = sK + 64 * LP;                        // [d][tok]
  unsigned short* sP  = sVt + 64 * LP;
  unsigned short* sH  = sP + 64 * LP;                        // O_h / U_h
  float* sSum  = (float*)(smem + 112640);                    // [8][64]
  float* sSq   = sSum + 512;                                 // [8][64]
  float* sMean = sSq + 512;                                  // [64]
  float* sRstd = sMean + 64;                                 // [64]
  float* sRedA = sRstd + 64;                                 // [2][64]
  float* sRedB = sRedA + 128;                                // [2][64]

  const int tid = threadIdx.x;
  const int wv = tid >> 6, lane = tid & 63;
  const int l16 = lane & 15, lg = lane >> 4;  // lane group 0..3

  const int wid = blockIdx.x;
  if (wid >= NWIN) return;
  const int b = wid / 144, rem = wid % 144;
  const int h0 = (rem / 12) * 8, w0 = (rem % 12) * 8;
  const float* xb = x + (size_t)b * 512 * 9216 + (size_t)h0 * 96 + w0;
  float* ob = out + (size_t)b * 512 * 9216 + (size_t)h0 * 96 + w0;

  const int mh = wv & 1;            // row half (A / F1 phases)
  const int nc16 = (wv >> 1) * 16;  // 16-col slice
  const int mt4 = wv & 3;           // row tile (S / PV phases)
  const int half2 = wv >> 2;        // col half
  const int ycol0 = wv * 64;        // this wave's 64 cols of C

  // ---- Phase 0: gather window -> sT (bf16) ----
#pragma unroll 4
  for (int it = 0; it < 64; ++it) {
    int c = it * 8 + wv;
    float v = xb[(size_t)c * 9216 + (lane >> 3) * 96 + (lane & 7)];
    sT[lane * CP + c] = f2bf(v);
  }
  __syncthreads();

  f32x4 Yacc[4][4] = {};  // persistent o-proj accumulator: [mt][nt]

  for (int h = 0; h < 8; ++h) {
    // ---- Phase A: q,k,v for head h (wave: 32 rows x 16 cols, all 3 mats) ----
    {
      const unsigned short* bq = WqkvT + (size_t)(h * 64 + nc16 + l16) * 512;
      const unsigned short* bk = bq + (size_t)512 * 512;
      const unsigned short* bv = bk + (size_t)512 * 512;
      f32x4 acc[3][2] = {};
      for (int ks = 0; ks < 16; ++ks) {
        const int ko = ks * 32 + lg * 8;
        short8 a0 = lds8(&sT[(mh * 32 + l16) * CP + ko]);
        short8 a1 = lds8(&sT[(mh * 32 + 16 + l16) * CP + ko]);
        short8 b0 = *(const short8*)(bq + ko);
        acc[0][0] = mfma16(a0, b0, acc[0][0]);
        acc[0][1] = mfma16(a1, b0, acc[0][1]);
        short8 b1 = *(const short8*)(bk + ko);
        acc[1][0] = mfma16(a0, b1, acc[1][0]);
        acc[1][1] = mfma16(a1, b1, acc[1][1]);
        short8 b2 = *(const short8*)(bv + ko);
        acc[2][0] = mfma16(a0, b2, acc[2][0]);
        acc[2][1] = mfma16(a1, b2, acc[2][1]);
      }
      const float bqv = bqkv[h * 64 + nc16 + l16];
      const float bkv = bqkv[512 + h * 64 + nc16 + l16];
      const float bvv = bqkv[1024 + h * 64 + nc16 + l16];
#pragma unroll
      for (int mt = 0; mt < 2; ++mt) {
        int tok0 = mh * 32 + mt * 16 + lg * 4;
#pragma unroll
        for (int r = 0; r < 4; ++r) {
          sQ[(tok0 + r) * LP + nc16 + l16] = f2bf((acc[0][mt][r] + bqv) * 0.125f);
          sK[(tok0 + r) * LP + nc16 + l16] = f2bf(acc[1][mt][r] + bkv);
        }
        ushort4 pk;
        pk.x = f2bf(acc[2][mt][0] + bvv);
        pk.y = f2bf(acc[2][mt][1] + bvv);
        pk.z = f2bf(acc[2][mt][2] + bvv);
        pk.w = f2bf(acc[2][mt][3] + bvv);
        *reinterpret_cast<ushort4*>(&sVt[(nc16 + l16) * LP + tok0]) = pk;
      }
    }
    __syncthreads();

    // ---- Phase S: scores + softmax (wave: 16 rows x 32 cols) ----
    {
      f32x4 sc0 = {0.f, 0.f, 0.f, 0.f}, sc1 = {0.f, 0.f, 0.f, 0.f};
#pragma unroll
      for (int ks = 0; ks < 2; ++ks) {
        int ko = ks * 32 + lg * 8;
        short8 a = lds8(&sQ[(mt4 * 16 + l16) * LP + ko]);
        short8 b0 = lds8(&sK[(half2 * 32 + l16) * LP + ko]);
        short8 b1 = lds8(&sK[(half2 * 32 + 16 + l16) * LP + ko]);
        sc0 = mfma16(a, b0, sc0);
        sc1 = mfma16(a, b1, sc1);
      }
#pragma unroll
      for (int r = 0; r < 4; ++r) {
        float m = fmaxf(sc0[r], sc1[r]);
        m = fmaxf(m, __shfl_xor(m, 1));
        m = fmaxf(m, __shfl_xor(m, 2));
        m = fmaxf(m, __shfl_xor(m, 4));
        m = fmaxf(m, __shfl_xor(m, 8));
        if (l16 == 0) sRedA[half2 * 64 + mt4 * 16 + lg * 4 + r] = m;
      }
      __syncthreads();
      float ex0[4], ex1[4];
#pragma unroll
      for (int r = 0; r < 4; ++r) {
        int row = mt4 * 16 + lg * 4 + r;
        float m = fmaxf(sRedA[row], sRedA[64 + row]);
        ex0[r] = __expf(sc0[r] - m);
        ex1[r] = __expf(sc1[r] - m);
        float s = ex0[r] + ex1[r];
        s += __shfl_xor(s, 1);
        s += __shfl_xor(s, 2);
        s += __shfl_xor(s, 4);
        s += __shfl_xor(s, 8);
        if (l16 == 0) sRedB[half2 * 64 + row] = s;
      }
      __syncthreads();
#pragma unroll
      for (int r = 0; r < 4; ++r) {
        int row = mt4 * 16 + lg * 4 + r;
        float inv = 1.0f / (sRedB[row] + sRedB[64 + row]);
        sP[row * LP + half2 * 32 + l16] = f2bf(ex0[r] * inv);
        sP[row * LP + half2 * 32 + 16 + l16] = f2bf(ex1[r] * inv);
      }
    }
    __syncthreads();

    // ---- Phase PV: O_h = P @ V ----
    {
      f32x4 ov0 = {0.f, 0.f, 0.f, 0.f}, ov1 = {0.f, 0.f, 0.f, 0.f};
#pragma unroll
      for (int ks = 0; ks < 2; ++ks) {
        int ko = ks * 32 + lg * 8;
        short8 a = lds8(&sP[(mt4 * 16 + l16) * LP + ko]);
        short8 b0 = lds8(&sVt[(half2 * 32 + l16) * LP + ko]);
        short8 b1 = lds8(&sVt[(half2 * 32 + 16 + l16) * LP + ko]);
        ov0 = mfma16(a, b0, ov0);
        ov1 = mfma16(a, b1, ov1);
      }
      int tok0 = mt4 * 16 + lg * 4;
#pragma unroll
      for (int r = 0; r < 4; ++r) {
        sH[(tok0 + r) * LP + half2 * 32 + l16] = f2bf(ov0[r]);
        sH[(tok0 + r) * LP + half2 * 32 + 16 + l16] = f2bf(ov1[r]);
      }
    }
    __syncthreads();

    // ---- Phase OP: Yacc += O_h @ Wo[h*64:(h+1)*64, ycol0:ycol0+64] ----
    {
      const unsigned short* wo0 = WoT + (size_t)(ycol0 + l16) * 512 + h * 64;
#pragma unroll
      for (int ks = 0; ks < 2; ++ks) {
        int ko = ks * 32 + lg * 8;
        short8 a0 = lds8(&sH[(l16) * LP + ko]);
        short8 a1 = lds8(&sH[(16 + l16) * LP + ko]);
        short8 a2 = lds8(&sH[(32 + l16) * LP + ko]);
        short8 a3 = lds8(&sH[(48 + l16) * LP + ko]);
#pragma unroll
        for (int nt = 0; nt < 4; ++nt) {
          short8 bb = *(const short8*)(wo0 + (size_t)nt * 16 * 512 + ko);
          Yacc[0][nt] = mfma16(a0, bb, Yacc[0][nt]);
          Yacc[1][nt] = mfma16(a1, bb, Yacc[1][nt]);
          Yacc[2][nt] = mfma16(a2, bb, Yacc[2][nt]);
          Yacc[3][nt] = mfma16(a3, bb, Yacc[3][nt]);
        }
      }
    }
    // no barrier needed: next phases touch disjoint LDS until next barriers
  }

  // ---- Residual 1 + LayerNorm 1 -> x1 (overwrites sT) ----
  {
#pragma unroll
    for (int nt = 0; nt < 4; ++nt) {
      float bv = bo[ycol0 + nt * 16 + l16];
      int col = ycol0 + nt * 16 + l16;
#pragma unroll
      for (int mt = 0; mt < 4; ++mt) {
        int row0 = mt * 16 + lg * 4;
#pragma unroll
        for (int r = 0; r < 4; ++r)
          Yacc[mt][nt][r] += bv + bf2f(sT[(row0 + r) * CP + col]);
      }
    }
#pragma unroll
    for (int mt = 0; mt < 4; ++mt) {
#pragma unroll
      for (int r = 0; r < 4; ++r) {
        float s = Yacc[mt][0][r] + Yacc[mt][1][r] + Yacc[mt][2][r] + Yacc[mt][3][r];
        float q = Yacc[mt][0][r] * Yacc[mt][0][r] + Yacc[mt][1][r] * Yacc[mt][1][r] +
                  Yacc[mt][2][r] * Yacc[mt][2][r] + Yacc[mt][3][r] * Yacc[mt][3][r];
        s += __shfl_xor(s, 1); s += __shfl_xor(s, 2);
        s += __shfl_xor(s, 4); s += __shfl_xor(s, 8);
        q += __shfl_xor(q, 1); q += __shfl_xor(q, 2);
        q += __shfl_xor(q, 4); q += __shfl_xor(q, 8);
        if (l16 == 0) {
          sSum[wv * 64 + mt * 16 + lg * 4 + r] = s;
          sSq[wv * 64 + mt * 16 + lg * 4 + r] = q;
        }
      }
    }
    __syncthreads();
    if (tid < 64) {
      float s = 0.f, q = 0.f;
#pragma unroll
      for (int w = 0; w < 8; ++w) { s += sSum[w * 64 + tid]; q += sSq[w * 64 + tid]; }
      float mean = s * (1.0f / 512.0f);
      float var = q * (1.0f / 512.0f) - mean * mean;
      sMean[tid] = mean;
      sRstd[tid] = rsqrtf(var + 1e-5f);
    }
    __syncthreads();
#pragma unroll
    for (int nt = 0; nt < 4; ++nt) {
      int col = ycol0 + nt * 16 + l16;
      float gv = g1[col], bv = beta1[col];
#pragma unroll
      for (int mt = 0; mt < 4; ++mt) {
        int row0 = mt * 16 + lg * 4;
#pragma unroll
        for (int r = 0; r < 4; ++r) {
          float xv = (Yacc[mt][nt][r] - sMean[row0 + r]) * sRstd[row0 + r] * gv + bv;
          sT[(row0 + r) * CP + col] = f2bf(xv);
        }
      }
    }
  }
  __syncthreads();

  // ---- FFN: 8 hidden chunks of 64 ----
  f32x4 Facc[4][4] = {};
  for (int hc = 0; hc < 8; ++hc) {
    // F1: u = relu(x1 @ W1[:, hc*64 + nc16 ..]) (wave: 32 rows x 16 cols)
    {
      const unsigned short* w1p = W1T + (size_t)(hc * 64 + nc16 + l16) * 512;
      f32x4 u0 = {0.f, 0.f, 0.f, 0.f}, u1 = {0.f, 0.f, 0.f, 0.f};
      for (int ks = 0; ks < 16; ++ks) {
        int ko = ks * 32 + lg * 8;
        short8 bb = *(const short8*)(w1p + ko);
        short8 a0 = lds8(&sT[(mh * 32 + l16) * CP + ko]);
        short8 a1 = lds8(&sT[(mh * 32 + 16 + l16) * CP + ko]);
        u0 = mfma16(a0, bb, u0);
        u1 = mfma16(a1, bb, u1);
      }
      float bv = bf1[hc * 64 + nc16 + l16];
      int tok0 = mh * 32 + lg * 4;
#pragma unroll
      for (int r = 0; r < 4; ++r) {
        sH[(tok0 + r) * LP + nc16 + l16] = f2bf(fmaxf(u0[r] + bv, 0.0f));
        sH[(tok0 + 16 + r) * LP + nc16 + l16] = f2bf(fmaxf(u1[r] + bv, 0.0f));
      }
    }
    __syncthreads();
    // F2: Facc += u @ W2[hc*64.., ycol0..]
    {
      const unsigned short* w2p = W2T + (size_t)(ycol0 + l16) * 512 + hc * 64;
#pragma unroll
      for (int ks = 0; ks < 2; ++ks) {
        int ko = ks * 32 + lg * 8;
        short8 a0 = lds8(&sH[(l16) * LP + ko]);
        short8 a1 = lds8(&sH[(16 + l16) * LP + ko]);
        short8 a2 = lds8(&sH[(32 + l16) * LP + ko]);
        short8 a3 = lds8(&sH[(48 + l16) * LP + ko]);
#pragma unroll
        for (int nt = 0; nt < 4; ++nt) {
          short8 bb = *(const short8*)(w2p + (size_t)nt * 16 * 512 + ko);
          Facc[0][nt] = mfma16(a0, bb, Facc[0][nt]);
          Facc[1][nt] = mfma16(a1, bb, Facc[1][nt]);
          Facc[2][nt] = mfma16(a2, bb, Facc[2][nt]);
          Facc[3][nt] = mfma16(a3, bb, Facc[3][nt]);
        }
      }
    }
    __syncthreads();  // sH reused next chunk
  }

  // ---- Residual 2 + LayerNorm 2 -> output ----
  {
#pragma unroll
    for (int nt = 0; nt < 4; ++nt) {
      float bv = bf2[ycol0 + nt * 16 + l16];
      int col = ycol0 + nt * 16 + l16;
#pragma unroll
      for (int mt = 0; mt < 4; ++mt) {
        int row0 = mt * 16 + lg * 4;
#pragma unroll
        for (int r = 0; r < 4; ++r)
          Facc[mt][nt][r] += bv + bf2f(sT[(row0 + r) * CP + col]);
      }
    }
#pragma unroll
    for (int mt = 0; mt < 4; ++mt) {
#pragma unroll
      for (int r = 0; r < 4; ++r) {
        float s = Facc[mt][0][r] + Facc[mt][1][r] + Facc[mt][2][r] + Facc[mt][3][r];
        float q = Facc[mt][0][r] * Facc[mt][0][r] + Facc[mt][1][r] * Facc[mt][1][r] +
                  Facc[mt][2][r] * Facc[mt][2][r] + Facc[mt][3][r] * Facc[mt][3][r];
        s += __shfl_xor(s, 1); s += __shfl_xor(s, 2);
        s += __shfl_xor(s, 4); s += __shfl_xor(s, 8);
        q += __shfl_xor(q, 1); q += __shfl_xor(q, 2);
        q += __shfl_xor(q, 4); q += __shfl_xor(q, 8);
        if (l16 == 0) {
          sSum[wv * 64 + mt * 16 + lg * 4 + r] = s;
          sSq[wv * 64 + mt * 16 + lg * 4 + r] = q;
        }
      }
    }
    __syncthreads();
    if (tid < 64) {
      float s = 0.f, q = 0.f;
#pragma unroll
      for (int w = 0; w < 8; ++w) { s += sSum[w * 64 + tid]; q += sSq[w * 64 + tid]; }
      float mean = s * (1.0f / 512.0f);
      float var = q * (1.0f / 512.0f) - mean * mean;
      sMean[tid] = mean;
      sRstd[tid] = rsqrtf(var + 1e-5f);
    }
    __syncthreads();
#pragma unroll
    for (int nt = 0; nt < 4; ++nt) {
      int col = ycol0 + nt * 16 + l16;
      float gv = g2[col], bv = beta2[col];
      float* op = ob + (size_t)col * 9216;
#pragma unroll
      for (int mt = 0; mt < 4; ++mt) {
        int tok0 = mt * 16 + lg * 4;
        float4 o4;
        o4.x = (Facc[mt][nt][0] - sMean[tok0 + 0]) * sRstd[tok0 + 0] * gv + bv;
        o4.y = (Facc[mt][nt][1] - sMean[tok0 + 1]) * sRstd[tok0 + 1] * gv + bv;
        o4.z = (Facc[mt][nt][2] - sMean[tok0 + 2]) * sRstd[tok0 + 2] * gv + bv;
        o4.w = (Facc[mt][nt][3] - sMean[tok0 + 3]) * sRstd[tok0 + 3] * gv + bv;
        *reinterpret_cast<float4*>(&op[(tok0 >> 3) * 96 + (tok0 & 7)]) = o4;
      }
    }
  }
}

extern "C" void kernel_launch(void* const* d_in, const int* in_sizes, int n_in,
                              void* d_out, int out_size, void* d_ws, size_t ws_size,
                              hipStream_t stream) {
  const float* x     = (const float*)d_in[0];
  const float* Wqkv  = (const float*)d_in[1];
  const float* bqkv  = (const float*)d_in[2];
  const float* Wo    = (const float*)d_in[3];
  const float* bo    = (const float*)d_in[4];
  const float* g1    = (const float*)d_in[5];
  const float* beta1 = (const float*)d_in[6];
  const float* W1    = (const float*)d_in[7];
  const float* bf1   = (const float*)d_in[8];
  const float* W2    = (const float*)d_in[9];
  const float* bf2   = (const float*)d_in[10];
  const float* g2    = (const float*)d_in[11];
  const float* beta2 = (const float*)d_in[12];
  float* out = (float*)d_out;

  unsigned short* ws = (unsigned short*)d_ws;
  unsigned short* WqkvT = ws;                          // 1536*512
  unsigned short* WoT   = ws + (size_t)1536 * 512;     // 512*512
  unsigned short* W1T   = WoT + (size_t)512 * 512;
  unsigned short* W2T   = W1T + (size_t)512 * 512;

  transpose_cvt_kernel<<<dim3(48, 16), 256, 0, stream>>>(Wqkv, WqkvT, 512, 1536);
  transpose_cvt_kernel<<<dim3(16, 16), 256, 0, stream>>>(Wo, WoT, 512, 512);
  transpose_cvt_kernel<<<dim3(16, 16), 256, 0, stream>>>(W1, W1T, 512, 512);
  transpose_cvt_kernel<<<dim3(16, 16), 256, 0, stream>>>(W2, W2T, 512, 512);

  (void)hipFuncSetAttribute((const void*)swin_fused,
                            hipFuncAttributeMaxDynamicSharedMemorySize, SMEM_BYTES);
  swin_fused<<<NWIN, 512, SMEM_BYTES, stream>>>(x, WqkvT, bqkv, WoT, bo, g1, beta1,
                                                W1T, bf1, W2T, bf2, g2, beta2, out);
}

// Round 2
// 1981.793 us; speedup vs baseline: 1.0329x; 1.0329x over previous
//
#include <hip/hip_runtime.h>

typedef short short8 __attribute__((ext_vector_type(8)));
typedef float f32x4 __attribute__((ext_vector_type(4)));

#define NWIN 2304
#define CP 520    // padded row (ushorts) for [64][512] token tile
#define LP2 136   // padded row (ushorts) for [64][128] two-head tiles
#define VTP 72    // padded row (ushorts) for sVt [128][64]
#define SMEM_BYTES 130560

static __device__ __forceinline__ unsigned short f2bf(float f) {
  unsigned int u = __float_as_uint(f);
  u += 0x7FFFu + ((u >> 16) & 1u);   // RNE
  return (unsigned short)(u >> 16);
}
static __device__ __forceinline__ float bf2f(unsigned short s) {
  return __uint_as_float(((unsigned int)s) << 16);
}
static __device__ __forceinline__ f32x4 mfma16(short8 a, short8 b, f32x4 c) {
  return __builtin_amdgcn_mfma_f32_16x16x32_bf16(a, b, c, 0, 0, 0);
}
static __device__ __forceinline__ short8 lds8(const unsigned short* p) {
  return *reinterpret_cast<const short8*>(p);
}

// ---- weight prep: in[K][N] f32  ->  out[N][K] bf16 ----
__global__ void transpose_cvt_kernel(const float* __restrict__ in,
                                     unsigned short* __restrict__ out,
                                     int K, int N) {
  __shared__ float tile[32][33];
  int bn = blockIdx.x * 32, bk = blockIdx.y * 32;
  int tx = threadIdx.x & 31, ty = threadIdx.x >> 5;  // 256 thr: 32 x 8
#pragma unroll
  for (int r = 0; r < 32; r += 8)
    tile[ty + r][tx] = in[(size_t)(bk + ty + r) * N + bn + tx];
  __syncthreads();
#pragma unroll
  for (int r = 0; r < 32; r += 8)
    out[(size_t)(bn + ty + r) * K + bk + tx] = f2bf(tile[tx][ty + r]);
}

__global__ __launch_bounds__(1024, 4)
void swin_fused(const float* __restrict__ x,
                const unsigned short* __restrict__ WqkvT,  // [1536][512] bf16
                const float* __restrict__ bqkv,
                const unsigned short* __restrict__ WoT,    // [512][512]
                const float* __restrict__ bo,
                const float* __restrict__ g1, const float* __restrict__ beta1,
                const unsigned short* __restrict__ W1T,    // [512][512]
                const float* __restrict__ bf1,
                const unsigned short* __restrict__ W2T,    // [512][512]
                const float* __restrict__ bf2,
                const float* __restrict__ g2, const float* __restrict__ beta2,
                float* __restrict__ out) {
  extern __shared__ unsigned char smem[];
  unsigned short* sT  = (unsigned short*)smem;               // [64][CP]
  unsigned short* sQ  = (unsigned short*)(smem + 66560);     // [64][LP2]
  unsigned short* sK  = (unsigned short*)(smem + 83968);     // [64][LP2]
  unsigned short* sVt = (unsigned short*)(smem + 101376);    // [128][VTP]
  unsigned short* sP  = sQ;   // alias: P written after last Q read + barrier
  unsigned short* sH  = sK;   // alias: O/hidden written after last K read + barrier
  float* sSum  = (float*)(smem + 119808);                    // [16][64]
  float* sSq   = (float*)(smem + 123904);                    // [16][64]
  float* sMean = (float*)(smem + 128000);                    // [64]
  float* sRstd = (float*)(smem + 128256);                    // [64]
  float* sRedA = (float*)(smem + 128512);                    // [2][2][64]
  float* sRedB = (float*)(smem + 129536);                    // [2][2][64]

  const int tid = threadIdx.x;
  const int wv = tid >> 6, lane = tid & 63;
  const int l16 = lane & 15, lg = lane >> 4;

  const int wid = blockIdx.x;
  const int b = wid / 144, rem = wid % 144;
  const int h0 = (rem / 12) * 8, w0 = (rem % 12) * 8;
  const float* xb = x + (size_t)b * 512 * 9216 + (size_t)h0 * 96 + w0;
  float* ob = out + (size_t)b * 512 * 9216 + (size_t)h0 * 96 + w0;

  const int mh = wv & 1;            // row half (A / F1 phases)
  const int cs8 = wv >> 1;          // 16-col slice within 128 (A / F1)
  const int hh = wv >> 3;           // head within pair (S / PV)
  const int mt4 = (wv >> 1) & 3;    // 16-row tile (S / PV)
  const int ct2 = wv & 1;           // 32-col half (S / PV)
  const int ycol0 = wv * 32;        // this wave's 32 cols of C (OP/LN/F2)

  // ---- Phase 0: gather window -> sT (bf16), float4 reads ----
#pragma unroll
  for (int it = 0; it < 8; ++it) {
    int gid = it * 1024 + tid;                 // gid = c*16 + hr*2 + wq
    int c = gid >> 4, hr = (gid >> 1) & 7, wq = gid & 1;
    float4 v = *reinterpret_cast<const float4*>(xb + (size_t)c * 9216 + hr * 96 + wq * 4);
    int tok = hr * 8 + wq * 4;
    sT[(tok + 0) * CP + c] = f2bf(v.x);
    sT[(tok + 1) * CP + c] = f2bf(v.y);
    sT[(tok + 2) * CP + c] = f2bf(v.z);
    sT[(tok + 3) * CP + c] = f2bf(v.w);
  }
  __syncthreads();

  f32x4 Yacc[4][2] = {};  // persistent o-proj accumulator: [row tile][nt]

  for (int hp = 0; hp < 4; ++hp) {   // head pairs
    // ---- Phase A: q,k,v for heads 2hp,2hp+1 (wave: 32 rows x 16 cols x 3 mats) ----
    {
      const int c2 = cs8 * 16 + l16;                 // col within 128
      const unsigned short* bq = WqkvT + (size_t)(hp * 128 + c2) * 512;
      const unsigned short* bk = bq + (size_t)512 * 512;
      const unsigned short* bv = bq + (size_t)1024 * 512;
      f32x4 acc[3][2] = {};
      for (int ks = 0; ks < 16; ++ks) {
        const int ko = ks * 32 + lg * 8;
        short8 a0 = lds8(&sT[(mh * 32 + l16) * CP + ko]);
        short8 a1 = lds8(&sT[(mh * 32 + 16 + l16) * CP + ko]);
        short8 b0 = *(const short8*)(bq + ko);
        acc[0][0] = mfma16(a0, b0, acc[0][0]);
        acc[0][1] = mfma16(a1, b0, acc[0][1]);
        short8 b1 = *(const short8*)(bk + ko);
        acc[1][0] = mfma16(a0, b1, acc[1][0]);
        acc[1][1] = mfma16(a1, b1, acc[1][1]);
        short8 b2 = *(const short8*)(bv + ko);
        acc[2][0] = mfma16(a0, b2, acc[2][0]);
        acc[2][1] = mfma16(a1, b2, acc[2][1]);
      }
      const float bqv = bqkv[hp * 128 + c2];
      const float bkv = bqkv[512 + hp * 128 + c2];
      const float bvv = bqkv[1024 + hp * 128 + c2];
#pragma unroll
      for (int mt2 = 0; mt2 < 2; ++mt2) {
        int tok0 = mh * 32 + mt2 * 16 + lg * 4;
#pragma unroll
        for (int r = 0; r < 4; ++r) {
          sQ[(tok0 + r) * LP2 + c2] = f2bf((acc[0][mt2][r] + bqv) * 0.125f);
          sK[(tok0 + r) * LP2 + c2] = f2bf(acc[1][mt2][r] + bkv);
        }
        ushort4 pk;
        pk.x = f2bf(acc[2][mt2][0] + bvv);
        pk.y = f2bf(acc[2][mt2][1] + bvv);
        pk.z = f2bf(acc[2][mt2][2] + bvv);
        pk.w = f2bf(acc[2][mt2][3] + bvv);
        *reinterpret_cast<ushort4*>(&sVt[c2 * VTP + tok0]) = pk;
      }
    }
    __syncthreads();

    // ---- Phase S: scores + softmax (wave: head hh, 16 rows x 32 cols) ----
    {
      f32x4 sc0 = {0.f, 0.f, 0.f, 0.f}, sc1 = {0.f, 0.f, 0.f, 0.f};
#pragma unroll
      for (int ks = 0; ks < 2; ++ks) {
        int ko = hh * 64 + ks * 32 + lg * 8;
        short8 a = lds8(&sQ[(mt4 * 16 + l16) * LP2 + ko]);
        short8 b0 = lds8(&sK[(ct2 * 32 + l16) * LP2 + ko]);
        short8 b1 = lds8(&sK[(ct2 * 32 + 16 + l16) * LP2 + ko]);
        sc0 = mfma16(a, b0, sc0);
        sc1 = mfma16(a, b1, sc1);
      }
#pragma unroll
      for (int r = 0; r < 4; ++r) {
        float m = fmaxf(sc0[r], sc1[r]);
        m = fmaxf(m, __shfl_xor(m, 1));
        m = fmaxf(m, __shfl_xor(m, 2));
        m = fmaxf(m, __shfl_xor(m, 4));
        m = fmaxf(m, __shfl_xor(m, 8));
        if (l16 == 0) sRedA[(hh * 2 + ct2) * 64 + mt4 * 16 + lg * 4 + r] = m;
      }
      __syncthreads();
      float ex0[4], ex1[4];
#pragma unroll
      for (int r = 0; r < 4; ++r) {
        int row = mt4 * 16 + lg * 4 + r;
        float m = fmaxf(sRedA[(hh * 2) * 64 + row], sRedA[(hh * 2 + 1) * 64 + row]);
        ex0[r] = __expf(sc0[r] - m);
        ex1[r] = __expf(sc1[r] - m);
        float s = ex0[r] + ex1[r];
        s += __shfl_xor(s, 1);
        s += __shfl_xor(s, 2);
        s += __shfl_xor(s, 4);
        s += __shfl_xor(s, 8);
        if (l16 == 0) sRedB[(hh * 2 + ct2) * 64 + row] = s;
      }
      __syncthreads();
#pragma unroll
      for (int r = 0; r < 4; ++r) {
        int row = mt4 * 16 + lg * 4 + r;
        float inv = 1.0f / (sRedB[(hh * 2) * 64 + row] + sRedB[(hh * 2 + 1) * 64 + row]);
        sP[row * LP2 + hh * 64 + ct2 * 32 + l16] = f2bf(ex0[r] * inv);
        sP[row * LP2 + hh * 64 + ct2 * 32 + 16 + l16] = f2bf(ex1[r] * inv);
      }
    }
    __syncthreads();

    // ---- Phase PV: O = P @ V (wave: head hh, 16 rows x 32 d-cols) ----
    {
      f32x4 ov0 = {0.f, 0.f, 0.f, 0.f}, ov1 = {0.f, 0.f, 0.f, 0.f};
#pragma unroll
      for (int ks = 0; ks < 2; ++ks) {
        int ko = ks * 32 + lg * 8;
        short8 a = lds8(&sP[(mt4 * 16 + l16) * LP2 + hh * 64 + ko]);
        short8 b0 = lds8(&sVt[(hh * 64 + ct2 * 32 + l16) * VTP + ko]);
        short8 b1 = lds8(&sVt[(hh * 64 + ct2 * 32 + 16 + l16) * VTP + ko]);
        ov0 = mfma16(a, b0, ov0);
        ov1 = mfma16(a, b1, ov1);
      }
      int tok0 = mt4 * 16 + lg * 4;
#pragma unroll
      for (int r = 0; r < 4; ++r) {
        sH[(tok0 + r) * LP2 + hh * 64 + ct2 * 32 + l16] = f2bf(ov0[r]);
        sH[(tok0 + r) * LP2 + hh * 64 + ct2 * 32 + 16 + l16] = f2bf(ov1[r]);
      }
    }
    __syncthreads();

    // ---- Phase OP: Yacc += O(2 heads) @ Wo[hp*128.., ycol0..+32] ----
    {
      const unsigned short* wo0 = WoT + (size_t)(ycol0 + l16) * 512 + hp * 128;
#pragma unroll
      for (int ks = 0; ks < 4; ++ks) {
        int ko = ks * 32 + lg * 8;
        short8 a0 = lds8(&sH[(l16) * LP2 + ko]);
        short8 a1 = lds8(&sH[(16 + l16) * LP2 + ko]);
        short8 a2 = lds8(&sH[(32 + l16) * LP2 + ko]);
        short8 a3 = lds8(&sH[(48 + l16) * LP2 + ko]);
#pragma unroll
        for (int nt = 0; nt < 2; ++nt) {
          short8 bb = *(const short8*)(wo0 + (size_t)nt * 16 * 512 + ko);
          Yacc[0][nt] = mfma16(a0, bb, Yacc[0][nt]);
          Yacc[1][nt] = mfma16(a1, bb, Yacc[1][nt]);
          Yacc[2][nt] = mfma16(a2, bb, Yacc[2][nt]);
          Yacc[3][nt] = mfma16(a3, bb, Yacc[3][nt]);
        }
      }
    }
    __syncthreads();  // sH (=sK) and sQ/sVt rewritten by next phase A
  }

  // ---- Residual 1 + LayerNorm 1 -> x1 (overwrites sT) ----
  {
#pragma unroll
    for (int nt = 0; nt < 2; ++nt) {
      int col = ycol0 + nt * 16 + l16;
      float bv = bo[col];
#pragma unroll
      for (int mt = 0; mt < 4; ++mt) {
        int row0 = mt * 16 + lg * 4;
#pragma unroll
        for (int r = 0; r < 4; ++r)
          Yacc[mt][nt][r] += bv + bf2f(sT[(row0 + r) * CP + col]);
      }
    }
#pragma unroll
    for (int mt = 0; mt < 4; ++mt) {
#pragma unroll
      for (int r = 0; r < 4; ++r) {
        float s = Yacc[mt][0][r] + Yacc[mt][1][r];
        float q = Yacc[mt][0][r] * Yacc[mt][0][r] + Yacc[mt][1][r] * Yacc[mt][1][r];
        s += __shfl_xor(s, 1); s += __shfl_xor(s, 2);
        s += __shfl_xor(s, 4); s += __shfl_xor(s, 8);
        q += __shfl_xor(q, 1); q += __shfl_xor(q, 2);
        q += __shfl_xor(q, 4); q += __shfl_xor(q, 8);
        if (l16 == 0) {
          sSum[wv * 64 + mt * 16 + lg * 4 + r] = s;
          sSq[wv * 64 + mt * 16 + lg * 4 + r] = q;
        }
      }
    }
    __syncthreads();
    if (tid < 64) {
      float s = 0.f, q = 0.f;
#pragma unroll
      for (int w = 0; w < 16; ++w) { s += sSum[w * 64 + tid]; q += sSq[w * 64 + tid]; }
      float mean = s * (1.0f / 512.0f);
      float var = q * (1.0f / 512.0f) - mean * mean;
      sMean[tid] = mean;
      sRstd[tid] = rsqrtf(var + 1e-5f);
    }
    __syncthreads();
#pragma unroll
    for (int nt = 0; nt < 2; ++nt) {
      int col = ycol0 + nt * 16 + l16;
      float gv = g1[col], bv = beta1[col];
#pragma unroll
      for (int mt = 0; mt < 4; ++mt) {
        int row0 = mt * 16 + lg * 4;
#pragma unroll
        for (int r = 0; r < 4; ++r) {
          float xv = (Yacc[mt][nt][r] - sMean[row0 + r]) * sRstd[row0 + r] * gv + bv;
          sT[(row0 + r) * CP + col] = f2bf(xv);
        }
      }
    }
  }
  __syncthreads();

  // ---- FFN: 4 hidden chunks of 128 ----
  f32x4 Facc[4][2] = {};
  for (int hc = 0; hc < 4; ++hc) {
    // F1: u = relu(x1 @ W1 chunk) (wave: 32 rows x 16 cols)
    {
      const int c2 = cs8 * 16 + l16;
      const int hcol = hc * 128 + c2;
      const unsigned short* w1p = W1T + (size_t)hcol * 512;
      f32x4 u0 = {0.f, 0.f, 0.f, 0.f}, u1 = {0.f, 0.f, 0.f, 0.f};
      for (int ks = 0; ks < 16; ++ks) {
        int ko = ks * 32 + lg * 8;
        short8 bb = *(const short8*)(w1p + ko);
        short8 a0 = lds8(&sT[(mh * 32 + l16) * CP + ko]);
        short8 a1 = lds8(&sT[(mh * 32 + 16 + l16) * CP + ko]);
        u0 = mfma16(a0, bb, u0);
        u1 = mfma16(a1, bb, u1);
      }
      float bv = bf1[hcol];
      int tok0 = mh * 32 + lg * 4;
#pragma unroll
      for (int r = 0; r < 4; ++r) {
        sH[(tok0 + r) * LP2 + c2] = f2bf(fmaxf(u0[r] + bv, 0.0f));
        sH[(tok0 + 16 + r) * LP2 + c2] = f2bf(fmaxf(u1[r] + bv, 0.0f));
      }
    }
    __syncthreads();
    // F2: Facc += u @ W2[hc*128.., ycol0..+32]
    {
      const unsigned short* w2p = W2T + (size_t)(ycol0 + l16) * 512 + hc * 128;
#pragma unroll
      for (int ks = 0; ks < 4; ++ks) {
        int ko = ks * 32 + lg * 8;
        short8 a0 = lds8(&sH[(l16) * LP2 + ko]);
        short8 a1 = lds8(&sH[(16 + l16) * LP2 + ko]);
        short8 a2 = lds8(&sH[(32 + l16) * LP2 + ko]);
        short8 a3 = lds8(&sH[(48 + l16) * LP2 + ko]);
#pragma unroll
        for (int nt = 0; nt < 2; ++nt) {
          short8 bb = *(const short8*)(w2p + (size_t)nt * 16 * 512 + ko);
          Facc[0][nt] = mfma16(a0, bb, Facc[0][nt]);
          Facc[1][nt] = mfma16(a1, bb, Facc[1][nt]);
          Facc[2][nt] = mfma16(a2, bb, Facc[2][nt]);
          Facc[3][nt] = mfma16(a3, bb, Facc[3][nt]);
        }
      }
    }
    __syncthreads();  // sH reused next chunk
  }

  // ---- Residual 2 + LayerNorm 2 -> output ----
  {
#pragma unroll
    for (int nt = 0; nt < 2; ++nt) {
      int col = ycol0 + nt * 16 + l16;
      float bv = bf2[col];
#pragma unroll
      for (int mt = 0; mt < 4; ++mt) {
        int row0 = mt * 16 + lg * 4;
#pragma unroll
        for (int r = 0; r < 4; ++r)
          Facc[mt][nt][r] += bv + bf2f(sT[(row0 + r) * CP + col]);
      }
    }
#pragma unroll
    for (int mt = 0; mt < 4; ++mt) {
#pragma unroll
      for (int r = 0; r < 4; ++r) {
        float s = Facc[mt][0][r] + Facc[mt][1][r];
        float q = Facc[mt][0][r] * Facc[mt][0][r] + Facc[mt][1][r] * Facc[mt][1][r];
        s += __shfl_xor(s, 1); s += __shfl_xor(s, 2);
        s += __shfl_xor(s, 4); s += __shfl_xor(s, 8);
        q += __shfl_xor(q, 1); q += __shfl_xor(q, 2);
        q += __shfl_xor(q, 4); q += __shfl_xor(q, 8);
        if (l16 == 0) {
          sSum[wv * 64 + mt * 16 + lg * 4 + r] = s;
          sSq[wv * 64 + mt * 16 + lg * 4 + r] = q;
        }
      }
    }
    __syncthreads();
    if (tid < 64) {
      float s = 0.f, q = 0.f;
#pragma unroll
      for (int w = 0; w < 16; ++w) { s += sSum[w * 64 + tid]; q += sSq[w * 64 + tid]; }
      float mean = s * (1.0f / 512.0f);
      float var = q * (1.0f / 512.0f) - mean * mean;
      sMean[tid] = mean;
      sRstd[tid] = rsqrtf(var + 1e-5f);
    }
    __syncthreads();
#pragma unroll
    for (int nt = 0; nt < 2; ++nt) {
      int col = ycol0 + nt * 16 + l16;
      float gv = g2[col], bv = beta2[col];
      float* op = ob + (size_t)col * 9216;
#pragma unroll
      for (int mt = 0; mt < 4; ++mt) {
        int tok0 = mt * 16 + lg * 4;
        float4 o4;
        o4.x = (Facc[mt][nt][0] - sMean[tok0 + 0]) * sRstd[tok0 + 0] * gv + bv;
        o4.y = (Facc[mt][nt][1] - sMean[tok0 + 1]) * sRstd[tok0 + 1] * gv + bv;
        o4.z = (Facc[mt][nt][2] - sMean[tok0 + 2]) * sRstd[tok0 + 2] * gv + bv;
        o4.w = (Facc[mt][nt][3] - sMean[tok0 + 3]) * sRstd[tok0 + 3] * gv + bv;
        *reinterpret_cast<float4*>(&op[(tok0 >> 3) * 96 + (tok0 & 7)]) = o4;
      }
    }
  }
}

extern "C" void kernel_launch(void* const* d_in, const int* in_sizes, int n_in,
                              void* d_out, int out_size, void* d_ws, size_t ws_size,
                              hipStream_t stream) {
  const float* x     = (const float*)d_in[0];
  const float* Wqkv  = (const float*)d_in[1];
  const float* bqkv  = (const float*)d_in[2];
  const float* Wo    = (const float*)d_in[3];
  const float* bo    = (const float*)d_in[4];
  const float* g1    = (const float*)d_in[5];
  const float* beta1 = (const float*)d_in[6];
  const float* W1    = (const float*)d_in[7];
  const float* bf1   = (const float*)d_in[8];
  const float* W2    = (const float*)d_in[9];
  const float* bf2   = (const float*)d_in[10];
  const float* g2    = (const float*)d_in[11];
  const float* beta2 = (const float*)d_in[12];
  float* out = (float*)d_out;

  unsigned short* ws = (unsigned short*)d_ws;
  unsigned short* WqkvT = ws;                          // 1536*512
  unsigned short* WoT   = ws + (size_t)1536 * 512;
  unsigned short* W1T   = WoT + (size_t)512 * 512;
  unsigned short* W2T   = W1T + (size_t)512 * 512;

  transpose_cvt_kernel<<<dim3(48, 16), 256, 0, stream>>>(Wqkv, WqkvT, 512, 1536);
  transpose_cvt_kernel<<<dim3(16, 16), 256, 0, stream>>>(Wo, WoT, 512, 512);
  transpose_cvt_kernel<<<dim3(16, 16), 256, 0, stream>>>(W1, W1T, 512, 512);
  transpose_cvt_kernel<<<dim3(16, 16), 256, 0, stream>>>(W2, W2T, 512, 512);

  (void)hipFuncSetAttribute((const void*)swin_fused,
                            hipFuncAttributeMaxDynamicSharedMemorySize, SMEM_BYTES);
  swin_fused<<<NWIN, 1024, SMEM_BYTES, stream>>>(x, WqkvT, bqkv, WoT, bo, g1, beta1,
                                                 W1T, bf1, W2T, bf2, g2, beta2, out);
}

// Round 3
// 1937.137 us; speedup vs baseline: 1.0567x; 1.0231x over previous
//
#include <hip/hip_runtime.h>

typedef short short8 __attribute__((ext_vector_type(8)));
typedef float f32x4 __attribute__((ext_vector_type(4)));

#define NWIN 2304
#define CP 520    // padded row (ushorts) for [64][512] token tile
#define LP2 136   // padded row (ushorts) for [64][128] two-head tiles
#define VTP 72    // padded row (ushorts) for sVt [128][64]
#define SMEM_BYTES 130560

static __device__ __forceinline__ unsigned short f2bf(float f) {
  unsigned int u = __float_as_uint(f);
  u += 0x7FFFu + ((u >> 16) & 1u);   // RNE
  return (unsigned short)(u >> 16);
}
static __device__ __forceinline__ float bf2f(unsigned short s) {
  return __uint_as_float(((unsigned int)s) << 16);
}
static __device__ __forceinline__ f32x4 mfma16(short8 a, short8 b, f32x4 c) {
  return __builtin_amdgcn_mfma_f32_16x16x32_bf16(a, b, c, 0, 0, 0);
}
static __device__ __forceinline__ short8 lds8(const unsigned short* p) {
  return *reinterpret_cast<const short8*>(p);
}

// ---- weight prep: in[K][N] f32  ->  out[N][K] bf16 ----
__global__ void transpose_cvt_kernel(const float* __restrict__ in,
                                     unsigned short* __restrict__ out,
                                     int K, int N) {
  __shared__ float tile[32][33];
  int bn = blockIdx.x * 32, bk = blockIdx.y * 32;
  int tx = threadIdx.x & 31, ty = threadIdx.x >> 5;  // 256 thr: 32 x 8
#pragma unroll
  for (int r = 0; r < 32; r += 8)
    tile[ty + r][tx] = in[(size_t)(bk + ty + r) * N + bn + tx];
  __syncthreads();
#pragma unroll
  for (int r = 0; r < 32; r += 8)
    out[(size_t)(bn + ty + r) * K + bk + tx] = f2bf(tile[tx][ty + r]);
}

__global__ __launch_bounds__(1024, 2)
void swin_fused(const float* __restrict__ x,
                const unsigned short* __restrict__ WqkvT,  // [1536][512] bf16
                const float* __restrict__ bqkv,
                const unsigned short* __restrict__ WoT,    // [512][512]
                const float* __restrict__ bo,
                const float* __restrict__ g1, const float* __restrict__ beta1,
                const unsigned short* __restrict__ W1T,    // [512][512]
                const float* __restrict__ bf1,
                const unsigned short* __restrict__ W2T,    // [512][512]
                const float* __restrict__ bf2,
                const float* __restrict__ g2, const float* __restrict__ beta2,
                float* __restrict__ out) {
  extern __shared__ unsigned char smem[];
  unsigned short* sT  = (unsigned short*)smem;               // [64][CP]
  unsigned short* sQ  = (unsigned short*)(smem + 66560);     // [64][LP2]
  unsigned short* sK  = (unsigned short*)(smem + 83968);     // [64][LP2]
  unsigned short* sVt = (unsigned short*)(smem + 101376);    // [128][VTP]
  unsigned short* sP  = sQ;   // alias: P written after last Q read + barrier
  unsigned short* sH  = sK;   // alias: O/hidden written after last K read + barrier
  float* sSum  = (float*)(smem + 119808);                    // [16][64]
  float* sSq   = (float*)(smem + 123904);                    // [16][64]
  float* sMean = (float*)(smem + 128000);                    // [64]
  float* sRstd = (float*)(smem + 128256);                    // [64]
  float* sRedA = (float*)(smem + 128512);                    // [2][2][64]
  float* sRedB = (float*)(smem + 129536);                    // [2][2][64]

  const int tid = threadIdx.x;
  const int wv = tid >> 6, lane = tid & 63;
  const int l16 = lane & 15, lg = lane >> 4;

  const int wid = blockIdx.x;
  const int b = wid / 144, rem = wid % 144;
  const int h0 = (rem / 12) * 8, w0 = (rem % 12) * 8;
  const float* xb = x + (size_t)b * 512 * 9216 + (size_t)h0 * 96 + w0;
  float* ob = out + (size_t)b * 512 * 9216 + (size_t)h0 * 96 + w0;

  const int mh = wv & 1;            // row half (A / F1 phases)
  const int cs8 = wv >> 1;          // 16-col slice within 128 (A / F1)
  const int hh = wv >> 3;           // head within pair (S / PV)
  const int mt4 = (wv >> 1) & 3;    // 16-row tile (S / PV)
  const int ct2 = wv & 1;           // 32-col half (S / PV)
  const int ycol0 = wv * 32;        // this wave's 32 cols of C (OP/LN/F2)

  // ---- Phase 0: gather window -> sT (bf16), float4 reads ----
#pragma unroll
  for (int it = 0; it < 8; ++it) {
    int gid = it * 1024 + tid;                 // gid = c*16 + hr*2 + wq
    int c = gid >> 4, hr = (gid >> 1) & 7, wq = gid & 1;
    float4 v = *reinterpret_cast<const float4*>(xb + (size_t)c * 9216 + hr * 96 + wq * 4);
    int tok = hr * 8 + wq * 4;
    sT[(tok + 0) * CP + c] = f2bf(v.x);
    sT[(tok + 1) * CP + c] = f2bf(v.y);
    sT[(tok + 2) * CP + c] = f2bf(v.z);
    sT[(tok + 3) * CP + c] = f2bf(v.w);
  }
  __syncthreads();

  f32x4 Yacc[4][2] = {};  // persistent o-proj accumulator: [row tile][nt]

  for (int hp = 0; hp < 4; ++hp) {   // head pairs
    // ---- Phase A: q,k,v for heads 2hp,2hp+1 (wave: 32 rows x 16 cols x 3 mats) ----
    {
      const int c2 = cs8 * 16 + l16;                 // col within 128
      const unsigned short* bq = WqkvT + (size_t)(hp * 128 + c2) * 512;
      const unsigned short* bk = bq + (size_t)512 * 512;
      const unsigned short* bv = bq + (size_t)1024 * 512;
      f32x4 acc[3][2] = {};
#pragma unroll 4
      for (int ks = 0; ks < 16; ++ks) {
        const int ko = ks * 32 + lg * 8;
        short8 a0 = lds8(&sT[(mh * 32 + l16) * CP + ko]);
        short8 a1 = lds8(&sT[(mh * 32 + 16 + l16) * CP + ko]);
        short8 b0 = *(const short8*)(bq + ko);
        acc[0][0] = mfma16(a0, b0, acc[0][0]);
        acc[0][1] = mfma16(a1, b0, acc[0][1]);
        short8 b1 = *(const short8*)(bk + ko);
        acc[1][0] = mfma16(a0, b1, acc[1][0]);
        acc[1][1] = mfma16(a1, b1, acc[1][1]);
        short8 b2 = *(const short8*)(bv + ko);
        acc[2][0] = mfma16(a0, b2, acc[2][0]);
        acc[2][1] = mfma16(a1, b2, acc[2][1]);
      }
      const float bqv = bqkv[hp * 128 + c2];
      const float bkv = bqkv[512 + hp * 128 + c2];
      const float bvv = bqkv[1024 + hp * 128 + c2];
#pragma unroll
      for (int mt2 = 0; mt2 < 2; ++mt2) {
        int tok0 = mh * 32 + mt2 * 16 + lg * 4;
#pragma unroll
        for (int r = 0; r < 4; ++r) {
          sQ[(tok0 + r) * LP2 + c2] = f2bf((acc[0][mt2][r] + bqv) * 0.125f);
          sK[(tok0 + r) * LP2 + c2] = f2bf(acc[1][mt2][r] + bkv);
        }
        ushort4 pk;
        pk.x = f2bf(acc[2][mt2][0] + bvv);
        pk.y = f2bf(acc[2][mt2][1] + bvv);
        pk.z = f2bf(acc[2][mt2][2] + bvv);
        pk.w = f2bf(acc[2][mt2][3] + bvv);
        *reinterpret_cast<ushort4*>(&sVt[c2 * VTP + tok0]) = pk;
      }
    }
    __syncthreads();

    // ---- Phase S: scores + softmax (wave: head hh, 16 rows x 32 cols) ----
    {
      f32x4 sc0 = {0.f, 0.f, 0.f, 0.f}, sc1 = {0.f, 0.f, 0.f, 0.f};
#pragma unroll
      for (int ks = 0; ks < 2; ++ks) {
        int ko = hh * 64 + ks * 32 + lg * 8;
        short8 a = lds8(&sQ[(mt4 * 16 + l16) * LP2 + ko]);
        short8 b0 = lds8(&sK[(ct2 * 32 + l16) * LP2 + ko]);
        short8 b1 = lds8(&sK[(ct2 * 32 + 16 + l16) * LP2 + ko]);
        sc0 = mfma16(a, b0, sc0);
        sc1 = mfma16(a, b1, sc1);
      }
#pragma unroll
      for (int r = 0; r < 4; ++r) {
        float m = fmaxf(sc0[r], sc1[r]);
        m = fmaxf(m, __shfl_xor(m, 1));
        m = fmaxf(m, __shfl_xor(m, 2));
        m = fmaxf(m, __shfl_xor(m, 4));
        m = fmaxf(m, __shfl_xor(m, 8));
        if (l16 == 0) sRedA[(hh * 2 + ct2) * 64 + mt4 * 16 + lg * 4 + r] = m;
      }
      __syncthreads();
      float ex0[4], ex1[4];
#pragma unroll
      for (int r = 0; r < 4; ++r) {
        int row = mt4 * 16 + lg * 4 + r;
        float m = fmaxf(sRedA[(hh * 2) * 64 + row], sRedA[(hh * 2 + 1) * 64 + row]);
        ex0[r] = __expf(sc0[r] - m);
        ex1[r] = __expf(sc1[r] - m);
        float s = ex0[r] + ex1[r];
        s += __shfl_xor(s, 1);
        s += __shfl_xor(s, 2);
        s += __shfl_xor(s, 4);
        s += __shfl_xor(s, 8);
        if (l16 == 0) sRedB[(hh * 2 + ct2) * 64 + row] = s;
      }
      __syncthreads();
#pragma unroll
      for (int r = 0; r < 4; ++r) {
        int row = mt4 * 16 + lg * 4 + r;
        float inv = 1.0f / (sRedB[(hh * 2) * 64 + row] + sRedB[(hh * 2 + 1) * 64 + row]);
        sP[row * LP2 + hh * 64 + ct2 * 32 + l16] = f2bf(ex0[r] * inv);
        sP[row * LP2 + hh * 64 + ct2 * 32 + 16 + l16] = f2bf(ex1[r] * inv);
      }
    }
    __syncthreads();

    // ---- Phase PV: O = P @ V (wave: head hh, 16 rows x 32 d-cols) ----
    {
      f32x4 ov0 = {0.f, 0.f, 0.f, 0.f}, ov1 = {0.f, 0.f, 0.f, 0.f};
#pragma unroll
      for (int ks = 0; ks < 2; ++ks) {
        int ko = ks * 32 + lg * 8;
        short8 a = lds8(&sP[(mt4 * 16 + l16) * LP2 + hh * 64 + ko]);
        short8 b0 = lds8(&sVt[(hh * 64 + ct2 * 32 + l16) * VTP + ko]);
        short8 b1 = lds8(&sVt[(hh * 64 + ct2 * 32 + 16 + l16) * VTP + ko]);
        ov0 = mfma16(a, b0, ov0);
        ov1 = mfma16(a, b1, ov1);
      }
      int tok0 = mt4 * 16 + lg * 4;
#pragma unroll
      for (int r = 0; r < 4; ++r) {
        sH[(tok0 + r) * LP2 + hh * 64 + ct2 * 32 + l16] = f2bf(ov0[r]);
        sH[(tok0 + r) * LP2 + hh * 64 + ct2 * 32 + 16 + l16] = f2bf(ov1[r]);
      }
    }
    __syncthreads();

    // ---- Phase OP: Yacc += O(2 heads) @ Wo[hp*128.., ycol0..+32] ----
    {
      const unsigned short* wo0 = WoT + (size_t)(ycol0 + l16) * 512 + hp * 128;
#pragma unroll
      for (int ks = 0; ks < 4; ++ks) {
        int ko = ks * 32 + lg * 8;
        short8 a0 = lds8(&sH[(l16) * LP2 + ko]);
        short8 a1 = lds8(&sH[(16 + l16) * LP2 + ko]);
        short8 a2 = lds8(&sH[(32 + l16) * LP2 + ko]);
        short8 a3 = lds8(&sH[(48 + l16) * LP2 + ko]);
#pragma unroll
        for (int nt = 0; nt < 2; ++nt) {
          short8 bb = *(const short8*)(wo0 + (size_t)nt * 16 * 512 + ko);
          Yacc[0][nt] = mfma16(a0, bb, Yacc[0][nt]);
          Yacc[1][nt] = mfma16(a1, bb, Yacc[1][nt]);
          Yacc[2][nt] = mfma16(a2, bb, Yacc[2][nt]);
          Yacc[3][nt] = mfma16(a3, bb, Yacc[3][nt]);
        }
      }
    }
    __syncthreads();  // sH (=sK) and sQ/sVt rewritten by next phase A
  }

  // ---- Residual 1 + LayerNorm 1 -> x1 (overwrites sT) ----
  {
#pragma unroll
    for (int nt = 0; nt < 2; ++nt) {
      int col = ycol0 + nt * 16 + l16;
      float bv = bo[col];
#pragma unroll
      for (int mt = 0; mt < 4; ++mt) {
        int row0 = mt * 16 + lg * 4;
#pragma unroll
        for (int r = 0; r < 4; ++r)
          Yacc[mt][nt][r] += bv + bf2f(sT[(row0 + r) * CP + col]);
      }
    }
#pragma unroll
    for (int mt = 0; mt < 4; ++mt) {
#pragma unroll
      for (int r = 0; r < 4; ++r) {
        float s = Yacc[mt][0][r] + Yacc[mt][1][r];
        float q = Yacc[mt][0][r] * Yacc[mt][0][r] + Yacc[mt][1][r] * Yacc[mt][1][r];
        s += __shfl_xor(s, 1); s += __shfl_xor(s, 2);
        s += __shfl_xor(s, 4); s += __shfl_xor(s, 8);
        q += __shfl_xor(q, 1); q += __shfl_xor(q, 2);
        q += __shfl_xor(q, 4); q += __shfl_xor(q, 8);
        if (l16 == 0) {
          sSum[wv * 64 + mt * 16 + lg * 4 + r] = s;
          sSq[wv * 64 + mt * 16 + lg * 4 + r] = q;
        }
      }
    }
    __syncthreads();
    if (tid < 64) {
      float s = 0.f, q = 0.f;
#pragma unroll
      for (int w = 0; w < 16; ++w) { s += sSum[w * 64 + tid]; q += sSq[w * 64 + tid]; }
      float mean = s * (1.0f / 512.0f);
      float var = q * (1.0f / 512.0f) - mean * mean;
      sMean[tid] = mean;
      sRstd[tid] = rsqrtf(var + 1e-5f);
    }
    __syncthreads();
#pragma unroll
    for (int nt = 0; nt < 2; ++nt) {
      int col = ycol0 + nt * 16 + l16;
      float gv = g1[col], bv = beta1[col];
#pragma unroll
      for (int mt = 0; mt < 4; ++mt) {
        int row0 = mt * 16 + lg * 4;
#pragma unroll
        for (int r = 0; r < 4; ++r) {
          float xv = (Yacc[mt][nt][r] - sMean[row0 + r]) * sRstd[row0 + r] * gv + bv;
          sT[(row0 + r) * CP + col] = f2bf(xv);
        }
      }
    }
  }
  __syncthreads();

  // ---- FFN: 4 hidden chunks of 128 ----
  f32x4 Facc[4][2] = {};
  for (int hc = 0; hc < 4; ++hc) {
    // F1: u = relu(x1 @ W1 chunk) (wave: 32 rows x 16 cols)
    {
      const int c2 = cs8 * 16 + l16;
      const int hcol = hc * 128 + c2;
      const unsigned short* w1p = W1T + (size_t)hcol * 512;
      f32x4 u0 = {0.f, 0.f, 0.f, 0.f}, u1 = {0.f, 0.f, 0.f, 0.f};
#pragma unroll 4
      for (int ks = 0; ks < 16; ++ks) {
        int ko = ks * 32 + lg * 8;
        short8 bb = *(const short8*)(w1p + ko);
        short8 a0 = lds8(&sT[(mh * 32 + l16) * CP + ko]);
        short8 a1 = lds8(&sT[(mh * 32 + 16 + l16) * CP + ko]);
        u0 = mfma16(a0, bb, u0);
        u1 = mfma16(a1, bb, u1);
      }
      float bv = bf1[hcol];
      int tok0 = mh * 32 + lg * 4;
#pragma unroll
      for (int r = 0; r < 4; ++r) {
        sH[(tok0 + r) * LP2 + c2] = f2bf(fmaxf(u0[r] + bv, 0.0f));
        sH[(tok0 + 16 + r) * LP2 + c2] = f2bf(fmaxf(u1[r] + bv, 0.0f));
      }
    }
    __syncthreads();
    // F2: Facc += u @ W2[hc*128.., ycol0..+32]
    {
      const unsigned short* w2p = W2T + (size_t)(ycol0 + l16) * 512 + hc * 128;
#pragma unroll
      for (int ks = 0; ks < 4; ++ks) {
        int ko = ks * 32 + lg * 8;
        short8 a0 = lds8(&sH[(l16) * LP2 + ko]);
        short8 a1 = lds8(&sH[(16 + l16) * LP2 + ko]);
        short8 a2 = lds8(&sH[(32 + l16) * LP2 + ko]);
        short8 a3 = lds8(&sH[(48 + l16) * LP2 + ko]);
#pragma unroll
        for (int nt = 0; nt < 2; ++nt) {
          short8 bb = *(const short8*)(w2p + (size_t)nt * 16 * 512 + ko);
          Facc[0][nt] = mfma16(a0, bb, Facc[0][nt]);
          Facc[1][nt] = mfma16(a1, bb, Facc[1][nt]);
          Facc[2][nt] = mfma16(a2, bb, Facc[2][nt]);
          Facc[3][nt] = mfma16(a3, bb, Facc[3][nt]);
        }
      }
    }
    __syncthreads();  // sH reused next chunk
  }

  // ---- Residual 2 + LayerNorm 2 -> output ----
  {
#pragma unroll
    for (int nt = 0; nt < 2; ++nt) {
      int col = ycol0 + nt * 16 + l16;
      float bv = bf2[col];
#pragma unroll
      for (int mt = 0; mt < 4; ++mt) {
        int row0 = mt * 16 + lg * 4;
#pragma unroll
        for (int r = 0; r < 4; ++r)
          Facc[mt][nt][r] += bv + bf2f(sT[(row0 + r) * CP + col]);
      }
    }
#pragma unroll
    for (int mt = 0; mt < 4; ++mt) {
#pragma unroll
      for (int r = 0; r < 4; ++r) {
        float s = Facc[mt][0][r] + Facc[mt][1][r];
        float q = Facc[mt][0][r] * Facc[mt][0][r] + Facc[mt][1][r] * Facc[mt][1][r];
        s += __shfl_xor(s, 1); s += __shfl_xor(s, 2);
        s += __shfl_xor(s, 4); s += __shfl_xor(s, 8);
        q += __shfl_xor(q, 1); q += __shfl_xor(q, 2);
        q += __shfl_xor(q, 4); q += __shfl_xor(q, 8);
        if (l16 == 0) {
          sSum[wv * 64 + mt * 16 + lg * 4 + r] = s;
          sSq[wv * 64 + mt * 16 + lg * 4 + r] = q;
        }
      }
    }
    __syncthreads();
    if (tid < 64) {
      float s = 0.f, q = 0.f;
#pragma unroll
      for (int w = 0; w < 16; ++w) { s += sSum[w * 64 + tid]; q += sSq[w * 64 + tid]; }
      float mean = s * (1.0f / 512.0f);
      float var = q * (1.0f / 512.0f) - mean * mean;
      sMean[tid] = mean;
      sRstd[tid] = rsqrtf(var + 1e-5f);
    }
    __syncthreads();
#pragma unroll
    for (int nt = 0; nt < 2; ++nt) {
      int col = ycol0 + nt * 16 + l16;
      float gv = g2[col], bv = beta2[col];
      float* op = ob + (size_t)col * 9216;
#pragma unroll
      for (int mt = 0; mt < 4; ++mt) {
        int tok0 = mt * 16 + lg * 4;
        float4 o4;
        o4.x = (Facc[mt][nt][0] - sMean[tok0 + 0]) * sRstd[tok0 + 0] * gv + bv;
        o4.y = (Facc[mt][nt][1] - sMean[tok0 + 1]) * sRstd[tok0 + 1] * gv + bv;
        o4.z = (Facc[mt][nt][2] - sMean[tok0 + 2]) * sRstd[tok0 + 2] * gv + bv;
        o4.w = (Facc[mt][nt][3] - sMean[tok0 + 3]) * sRstd[tok0 + 3] * gv + bv;
        *reinterpret_cast<float4*>(&op[(tok0 >> 3) * 96 + (tok0 & 7)]) = o4;
      }
    }
  }
}

extern "C" void kernel_launch(void* const* d_in, const int* in_sizes, int n_in,
                              void* d_out, int out_size, void* d_ws, size_t ws_size,
                              hipStream_t stream) {
  const float* x     = (const float*)d_in[0];
  const float* Wqkv  = (const float*)d_in[1];
  const float* bqkv  = (const float*)d_in[2];
  const float* Wo    = (const float*)d_in[3];
  const float* bo    = (const float*)d_in[4];
  const float* g1    = (const float*)d_in[5];
  const float* beta1 = (const float*)d_in[6];
  const float* W1    = (const float*)d_in[7];
  const float* bf1   = (const float*)d_in[8];
  const float* W2    = (const float*)d_in[9];
  const float* bf2   = (const float*)d_in[10];
  const float* g2    = (const float*)d_in[11];
  const float* beta2 = (const float*)d_in[12];
  float* out = (float*)d_out;

  unsigned short* ws = (unsigned short*)d_ws;
  unsigned short* WqkvT = ws;                          // 1536*512
  unsigned short* WoT   = ws + (size_t)1536 * 512;
  unsigned short* W1T   = WoT + (size_t)512 * 512;
  unsigned short* W2T   = W1T + (size_t)512 * 512;

  transpose_cvt_kernel<<<dim3(48, 16), 256, 0, stream>>>(Wqkv, WqkvT, 512, 1536);
  transpose_cvt_kernel<<<dim3(16, 16), 256, 0, stream>>>(Wo, WoT, 512, 512);
  transpose_cvt_kernel<<<dim3(16, 16), 256, 0, stream>>>(W1, W1T, 512, 512);
  transpose_cvt_kernel<<<dim3(16, 16), 256, 0, stream>>>(W2, W2T, 512, 512);

  (void)hipFuncSetAttribute((const void*)swin_fused,
                            hipFuncAttributeMaxDynamicSharedMemorySize, SMEM_BYTES);
  swin_fused<<<NWIN, 1024, SMEM_BYTES, stream>>>(x, WqkvT, bqkv, WoT, bo, g1, beta1,
                                                 W1T, bf1, W2T, bf2, g2, beta2, out);
}

// Round 4
// 1174.178 us; speedup vs baseline: 1.7434x; 1.6498x over previous
//
#include <hip/hip_runtime.h>

typedef short short8 __attribute__((ext_vector_type(8)));
typedef float f32x4 __attribute__((ext_vector_type(4)));

#define NWIN 2304
#define CP 520    // padded row (ushorts) for [64][512] token tile
#define LP2 136   // padded row (ushorts) for [64][128] tiles (Q/P/O, K/H)
#define VTP 72    // padded row (ushorts) for sVt [128][64]
#define SMEM_BYTES 124416

static __device__ __forceinline__ unsigned short f2bf(float f) {
  unsigned int u = __float_as_uint(f);
  u += 0x7FFFu + ((u >> 16) & 1u);   // RNE
  return (unsigned short)(u >> 16);
}
static __device__ __forceinline__ float bf2f(unsigned short s) {
  return __uint_as_float(((unsigned int)s) << 16);
}
static __device__ __forceinline__ f32x4 mfma16(short8 a, short8 b, f32x4 c) {
  return __builtin_amdgcn_mfma_f32_16x16x32_bf16(a, b, c, 0, 0, 0);
}
static __device__ __forceinline__ short8 lds8(const unsigned short* p) {
  return *reinterpret_cast<const short8*>(p);
}

// ---- weight prep: in[K][N] f32  ->  out[N][K] bf16 ----
__global__ void transpose_cvt_kernel(const float* __restrict__ in,
                                     unsigned short* __restrict__ out,
                                     int K, int N) {
  __shared__ float tile[32][33];
  int bn = blockIdx.x * 32, bk = blockIdx.y * 32;
  int tx = threadIdx.x & 31, ty = threadIdx.x >> 5;  // 256 thr: 32 x 8
#pragma unroll
  for (int r = 0; r < 32; r += 8)
    tile[ty + r][tx] = in[(size_t)(bk + ty + r) * N + bn + tx];
  __syncthreads();
#pragma unroll
  for (int r = 0; r < 32; r += 8)
    out[(size_t)(bn + ty + r) * K + bk + tx] = f2bf(tile[tx][ty + r]);
}

__global__ __launch_bounds__(512, 2)
void swin_fused(const float* __restrict__ x,
                const unsigned short* __restrict__ WqkvT,  // [1536][512] bf16
                const float* __restrict__ bqkv,
                const unsigned short* __restrict__ WoT,    // [512][512]
                const float* __restrict__ bo,
                const float* __restrict__ g1, const float* __restrict__ beta1,
                const unsigned short* __restrict__ W1T,    // [512][512]
                const float* __restrict__ bf1,
                const unsigned short* __restrict__ W2T,    // [512][512]
                const float* __restrict__ bf2,
                const float* __restrict__ g2, const float* __restrict__ beta2,
                float* __restrict__ out) {
  extern __shared__ unsigned char smem[];
  unsigned short* sT  = (unsigned short*)smem;               // [64][CP]
  unsigned short* sQ  = (unsigned short*)(smem + 66560);     // [64][LP2]  Q -> P -> O
  unsigned short* sK  = (unsigned short*)(smem + 83968);     // [64][LP2]  K / hidden
  unsigned short* sVt = (unsigned short*)(smem + 101376);    // [128][VTP]
  unsigned short* sH  = sK;
  float* sSum  = (float*)(smem + 119808);                    // [8][64]
  float* sSq   = (float*)(smem + 121856);                    // [8][64]
  float* sMean = (float*)(smem + 123904);                    // [64]
  float* sRstd = (float*)(smem + 124160);                    // [64]

  const int tid = threadIdx.x;
  const int wvid = tid >> 6, lane = tid & 63;
  const int l16 = lane & 15, lg = lane >> 4;

  // XCD swizzle: adjacent logical windows on the same XCD (share x cache lines)
  const int wid = (blockIdx.x & 7) * 288 + (blockIdx.x >> 3);
  const int b = wid / 144, rem = wid % 144;
  const int h0 = (rem / 12) * 8, w0 = (rem % 12) * 8;
  const float* xb = x + (size_t)b * 512 * 9216 + (size_t)h0 * 96 + w0;
  float* ob = out + (size_t)b * 512 * 9216 + (size_t)h0 * 96 + w0;

  const int c2 = wvid * 16 + l16;   // wave's 16-col slice (A / F1)
  const int hh = wvid >> 2;         // head within pair (S / PV)
  const int mt4 = wvid & 3;         // 16-row tile (S / PV)
  const int ycol0 = wvid * 64;      // wave's 64 C-cols (OP / LN / F2)

  // ---- Phase 0: gather window -> sT (bf16), float4 reads ----
#pragma unroll
  for (int it = 0; it < 16; ++it) {
    int gid = it * 512 + tid;                 // gid = c*16 + hr*2 + wq
    int c = gid >> 4, hr = (gid >> 1) & 7, wq = gid & 1;
    float4 v = *reinterpret_cast<const float4*>(xb + (size_t)c * 9216 + hr * 96 + wq * 4);
    int tok = hr * 8 + wq * 4;
    sT[(tok + 0) * CP + c] = f2bf(v.x);
    sT[(tok + 1) * CP + c] = f2bf(v.y);
    sT[(tok + 2) * CP + c] = f2bf(v.z);
    sT[(tok + 3) * CP + c] = f2bf(v.w);
  }
  __syncthreads();

  f32x4 Yacc[4][4] = {};  // persistent o-proj accumulator [row tile][col tile]

  for (int hp = 0; hp < 4; ++hp) {   // head pairs
    // ---- Phase A: q,k,v (wave: 64 rows x 16 cols x 3 mats, depth-4 prefetch) ----
    {
      const unsigned short* bq = WqkvT + (size_t)(hp * 128 + c2) * 512;
      const unsigned short* bk = bq + (size_t)512 * 512;
      const unsigned short* bv = bq + (size_t)1024 * 512;
      f32x4 acc[3][4] = {};
      short8 qw[4], kw[4], vw[4];
#pragma unroll
      for (int p = 0; p < 4; ++p) {
        int ko = p * 32 + lg * 8;
        qw[p] = *(const short8*)(bq + ko);
        kw[p] = *(const short8*)(bk + ko);
        vw[p] = *(const short8*)(bv + ko);
      }
#pragma unroll
      for (int ks = 0; ks < 16; ++ks) {
        const int ko = ks * 32 + lg * 8;
        short8 cq = qw[ks & 3], ck = kw[ks & 3], cv = vw[ks & 3];
        if (ks < 12) {
          int ko2 = (ks + 4) * 32 + lg * 8;
          qw[ks & 3] = *(const short8*)(bq + ko2);
          kw[ks & 3] = *(const short8*)(bk + ko2);
          vw[ks & 3] = *(const short8*)(bv + ko2);
        }
        short8 a0 = lds8(&sT[(l16) * CP + ko]);
        short8 a1 = lds8(&sT[(16 + l16) * CP + ko]);
        short8 a2 = lds8(&sT[(32 + l16) * CP + ko]);
        short8 a3 = lds8(&sT[(48 + l16) * CP + ko]);
        acc[0][0] = mfma16(a0, cq, acc[0][0]);
        acc[0][1] = mfma16(a1, cq, acc[0][1]);
        acc[0][2] = mfma16(a2, cq, acc[0][2]);
        acc[0][3] = mfma16(a3, cq, acc[0][3]);
        acc[1][0] = mfma16(a0, ck, acc[1][0]);
        acc[1][1] = mfma16(a1, ck, acc[1][1]);
        acc[1][2] = mfma16(a2, ck, acc[1][2]);
        acc[1][3] = mfma16(a3, ck, acc[1][3]);
        acc[2][0] = mfma16(a0, cv, acc[2][0]);
        acc[2][1] = mfma16(a1, cv, acc[2][1]);
        acc[2][2] = mfma16(a2, cv, acc[2][2]);
        acc[2][3] = mfma16(a3, cv, acc[2][3]);
      }
      const float bqv = bqkv[hp * 128 + c2];
      const float bkv = bqkv[512 + hp * 128 + c2];
      const float bvv = bqkv[1024 + hp * 128 + c2];
#pragma unroll
      for (int mt = 0; mt < 4; ++mt) {
        int tok0 = mt * 16 + lg * 4;
#pragma unroll
        for (int r = 0; r < 4; ++r) {
          sQ[(tok0 + r) * LP2 + c2] = f2bf((acc[0][mt][r] + bqv) * 0.125f);
          sK[(tok0 + r) * LP2 + c2] = f2bf(acc[1][mt][r] + bkv);
        }
        ushort4 pk;
        pk.x = f2bf(acc[2][mt][0] + bvv);
        pk.y = f2bf(acc[2][mt][1] + bvv);
        pk.z = f2bf(acc[2][mt][2] + bvv);
        pk.w = f2bf(acc[2][mt][3] + bvv);
        *reinterpret_cast<ushort4*>(&sVt[c2 * VTP + tok0]) = pk;
      }
    }
    __syncthreads();

    // ---- Phase S: scores + wave-local softmax (wave: head hh, rows mt4*16..) ----
    {
      f32x4 sc[4] = {};
#pragma unroll
      for (int ks = 0; ks < 2; ++ks) {
        int ko = hh * 64 + ks * 32 + lg * 8;
        short8 a  = lds8(&sQ[(mt4 * 16 + l16) * LP2 + ko]);
        short8 b0 = lds8(&sK[(l16) * LP2 + ko]);
        short8 b1 = lds8(&sK[(16 + l16) * LP2 + ko]);
        short8 b2 = lds8(&sK[(32 + l16) * LP2 + ko]);
        short8 b3 = lds8(&sK[(48 + l16) * LP2 + ko]);
        sc[0] = mfma16(a, b0, sc[0]);
        sc[1] = mfma16(a, b1, sc[1]);
        sc[2] = mfma16(a, b2, sc[2]);
        sc[3] = mfma16(a, b3, sc[3]);
      }
#pragma unroll
      for (int r = 0; r < 4; ++r) {
        float m = fmaxf(fmaxf(sc[0][r], sc[1][r]), fmaxf(sc[2][r], sc[3][r]));
        m = fmaxf(m, __shfl_xor(m, 1));
        m = fmaxf(m, __shfl_xor(m, 2));
        m = fmaxf(m, __shfl_xor(m, 4));
        m = fmaxf(m, __shfl_xor(m, 8));
        float e0 = __expf(sc[0][r] - m), e1 = __expf(sc[1][r] - m);
        float e2 = __expf(sc[2][r] - m), e3 = __expf(sc[3][r] - m);
        float s = e0 + e1 + e2 + e3;
        s += __shfl_xor(s, 1);
        s += __shfl_xor(s, 2);
        s += __shfl_xor(s, 4);
        s += __shfl_xor(s, 8);
        float inv = 1.0f / s;
        int row = mt4 * 16 + lg * 4 + r;
        sQ[row * LP2 + hh * 64 + l16]      = f2bf(e0 * inv);  // P over Q (own region)
        sQ[row * LP2 + hh * 64 + 16 + l16] = f2bf(e1 * inv);
        sQ[row * LP2 + hh * 64 + 32 + l16] = f2bf(e2 * inv);
        sQ[row * LP2 + hh * 64 + 48 + l16] = f2bf(e3 * inv);
      }
    }
    // no barrier: P produced and consumed by the same wave

    // ---- Phase PV: O = P @ V (write O over P, own region) ----
    {
      f32x4 ov[4] = {};
#pragma unroll
      for (int ks = 0; ks < 2; ++ks) {
        int ko = ks * 32 + lg * 8;
        short8 a  = lds8(&sQ[(mt4 * 16 + l16) * LP2 + hh * 64 + ko]);
        short8 b0 = lds8(&sVt[(hh * 64 + l16) * VTP + ko]);
        short8 b1 = lds8(&sVt[(hh * 64 + 16 + l16) * VTP + ko]);
        short8 b2 = lds8(&sVt[(hh * 64 + 32 + l16) * VTP + ko]);
        short8 b3 = lds8(&sVt[(hh * 64 + 48 + l16) * VTP + ko]);
        ov[0] = mfma16(a, b0, ov[0]);
        ov[1] = mfma16(a, b1, ov[1]);
        ov[2] = mfma16(a, b2, ov[2]);
        ov[3] = mfma16(a, b3, ov[3]);
      }
#pragma unroll
      for (int r = 0; r < 4; ++r) {
        int row = mt4 * 16 + lg * 4 + r;
        sQ[row * LP2 + hh * 64 + l16]      = f2bf(ov[0][r]);
        sQ[row * LP2 + hh * 64 + 16 + l16] = f2bf(ov[1][r]);
        sQ[row * LP2 + hh * 64 + 32 + l16] = f2bf(ov[2][r]);
        sQ[row * LP2 + hh * 64 + 48 + l16] = f2bf(ov[3][r]);
      }
    }
    __syncthreads();

    // ---- Phase OP: Yacc += O(2 heads) @ Wo[hp*128.., ycol0..+64] ----
    {
      const unsigned short* wo0 = WoT + (size_t)(ycol0 + l16) * 512 + hp * 128;
      short8 wb[4][4];
#pragma unroll
      for (int ks = 0; ks < 4; ++ks)
#pragma unroll
        for (int nt = 0; nt < 4; ++nt)
          wb[ks][nt] = *(const short8*)(wo0 + (size_t)nt * 16 * 512 + ks * 32 + lg * 8);
#pragma unroll
      for (int ks = 0; ks < 4; ++ks) {
        int ko = ks * 32 + lg * 8;
        short8 a0 = lds8(&sQ[(l16) * LP2 + ko]);
        short8 a1 = lds8(&sQ[(16 + l16) * LP2 + ko]);
        short8 a2 = lds8(&sQ[(32 + l16) * LP2 + ko]);
        short8 a3 = lds8(&sQ[(48 + l16) * LP2 + ko]);
#pragma unroll
        for (int nt = 0; nt < 4; ++nt) {
          Yacc[0][nt] = mfma16(a0, wb[ks][nt], Yacc[0][nt]);
          Yacc[1][nt] = mfma16(a1, wb[ks][nt], Yacc[1][nt]);
          Yacc[2][nt] = mfma16(a2, wb[ks][nt], Yacc[2][nt]);
          Yacc[3][nt] = mfma16(a3, wb[ks][nt], Yacc[3][nt]);
        }
      }
    }
    __syncthreads();  // next Phase A rewrites sQ/sK/sVt
  }

  // ---- Residual 1 + LayerNorm 1 -> x1 (overwrites sT) ----
  {
#pragma unroll
    for (int nt = 0; nt < 4; ++nt) {
      int col = ycol0 + nt * 16 + l16;
      float bv = bo[col];
#pragma unroll
      for (int mt = 0; mt < 4; ++mt) {
        int row0 = mt * 16 + lg * 4;
#pragma unroll
        for (int r = 0; r < 4; ++r)
          Yacc[mt][nt][r] += bv + bf2f(sT[(row0 + r) * CP + col]);
      }
    }
#pragma unroll
    for (int mt = 0; mt < 4; ++mt) {
#pragma unroll
      for (int r = 0; r < 4; ++r) {
        float s = Yacc[mt][0][r] + Yacc[mt][1][r] + Yacc[mt][2][r] + Yacc[mt][3][r];
        float q = Yacc[mt][0][r] * Yacc[mt][0][r] + Yacc[mt][1][r] * Yacc[mt][1][r] +
                  Yacc[mt][2][r] * Yacc[mt][2][r] + Yacc[mt][3][r] * Yacc[mt][3][r];
        s += __shfl_xor(s, 1); s += __shfl_xor(s, 2);
        s += __shfl_xor(s, 4); s += __shfl_xor(s, 8);
        q += __shfl_xor(q, 1); q += __shfl_xor(q, 2);
        q += __shfl_xor(q, 4); q += __shfl_xor(q, 8);
        if (l16 == 0) {
          sSum[wvid * 64 + mt * 16 + lg * 4 + r] = s;
          sSq[wvid * 64 + mt * 16 + lg * 4 + r] = q;
        }
      }
    }
    __syncthreads();
    if (tid < 64) {
      float s = 0.f, q = 0.f;
#pragma unroll
      for (int w = 0; w < 8; ++w) { s += sSum[w * 64 + tid]; q += sSq[w * 64 + tid]; }
      float mean = s * (1.0f / 512.0f);
      float var = q * (1.0f / 512.0f) - mean * mean;
      sMean[tid] = mean;
      sRstd[tid] = rsqrtf(var + 1e-5f);
    }
    __syncthreads();
#pragma unroll
    for (int nt = 0; nt < 4; ++nt) {
      int col = ycol0 + nt * 16 + l16;
      float gv = g1[col], bv = beta1[col];
#pragma unroll
      for (int mt = 0; mt < 4; ++mt) {
        int row0 = mt * 16 + lg * 4;
#pragma unroll
        for (int r = 0; r < 4; ++r) {
          float xv = (Yacc[mt][nt][r] - sMean[row0 + r]) * sRstd[row0 + r] * gv + bv;
          sT[(row0 + r) * CP + col] = f2bf(xv);
        }
      }
    }
  }
  __syncthreads();

  // ---- FFN: 4 hidden chunks of 128 ----
  f32x4 Facc[4][4] = {};
  for (int hc = 0; hc < 4; ++hc) {
    // F1: u = relu(x1 @ W1 chunk) (wave: 64 rows x 16 cols, depth-4 prefetch)
    {
      const int hcol = hc * 128 + c2;
      const unsigned short* w1p = W1T + (size_t)hcol * 512;
      f32x4 u[4] = {};
      short8 wbuf[4];
#pragma unroll
      for (int p = 0; p < 4; ++p)
        wbuf[p] = *(const short8*)(w1p + p * 32 + lg * 8);
#pragma unroll
      for (int ks = 0; ks < 16; ++ks) {
        int ko = ks * 32 + lg * 8;
        short8 cw = wbuf[ks & 3];
        if (ks < 12)
          wbuf[ks & 3] = *(const short8*)(w1p + (ks + 4) * 32 + lg * 8);
        short8 a0 = lds8(&sT[(l16) * CP + ko]);
        short8 a1 = lds8(&sT[(16 + l16) * CP + ko]);
        short8 a2 = lds8(&sT[(32 + l16) * CP + ko]);
        short8 a3 = lds8(&sT[(48 + l16) * CP + ko]);
        u[0] = mfma16(a0, cw, u[0]);
        u[1] = mfma16(a1, cw, u[1]);
        u[2] = mfma16(a2, cw, u[2]);
        u[3] = mfma16(a3, cw, u[3]);
      }
      float bv = bf1[hcol];
#pragma unroll
      for (int mt = 0; mt < 4; ++mt) {
        int tok0 = mt * 16 + lg * 4;
#pragma unroll
        for (int r = 0; r < 4; ++r)
          sH[(tok0 + r) * LP2 + c2] = f2bf(fmaxf(u[mt][r] + bv, 0.0f));
      }
    }
    __syncthreads();
    // F2: Facc += u @ W2[hc*128.., ycol0..+64]
    {
      const unsigned short* w2p = W2T + (size_t)(ycol0 + l16) * 512 + hc * 128;
      short8 wb[4][4];
#pragma unroll
      for (int ks = 0; ks < 4; ++ks)
#pragma unroll
        for (int nt = 0; nt < 4; ++nt)
          wb[ks][nt] = *(const short8*)(w2p + (size_t)nt * 16 * 512 + ks * 32 + lg * 8);
#pragma unroll
      for (int ks = 0; ks < 4; ++ks) {
        int ko = ks * 32 + lg * 8;
        short8 a0 = lds8(&sH[(l16) * LP2 + ko]);
        short8 a1 = lds8(&sH[(16 + l16) * LP2 + ko]);
        short8 a2 = lds8(&sH[(32 + l16) * LP2 + ko]);
        short8 a3 = lds8(&sH[(48 + l16) * LP2 + ko]);
#pragma unroll
        for (int nt = 0; nt < 4; ++nt) {
          Facc[0][nt] = mfma16(a0, wb[ks][nt], Facc[0][nt]);
          Facc[1][nt] = mfma16(a1, wb[ks][nt], Facc[1][nt]);
          Facc[2][nt] = mfma16(a2, wb[ks][nt], Facc[2][nt]);
          Facc[3][nt] = mfma16(a3, wb[ks][nt], Facc[3][nt]);
        }
      }
    }
    __syncthreads();  // sH reused next chunk
  }

  // ---- Residual 2 + LayerNorm 2 -> output ----
  {
#pragma unroll
    for (int nt = 0; nt < 4; ++nt) {
      int col = ycol0 + nt * 16 + l16;
      float bv = bf2[col];
#pragma unroll
      for (int mt = 0; mt < 4; ++mt) {
        int row0 = mt * 16 + lg * 4;
#pragma unroll
        for (int r = 0; r < 4; ++r)
          Facc[mt][nt][r] += bv + bf2f(sT[(row0 + r) * CP + col]);
      }
    }
#pragma unroll
    for (int mt = 0; mt < 4; ++mt) {
#pragma unroll
      for (int r = 0; r < 4; ++r) {
        float s = Facc[mt][0][r] + Facc[mt][1][r] + Facc[mt][2][r] + Facc[mt][3][r];
        float q = Facc[mt][0][r] * Facc[mt][0][r] + Facc[mt][1][r] * Facc[mt][1][r] +
                  Facc[mt][2][r] * Facc[mt][2][r] + Facc[mt][3][r] * Facc[mt][3][r];
        s += __shfl_xor(s, 1); s += __shfl_xor(s, 2);
        s += __shfl_xor(s, 4); s += __shfl_xor(s, 8);
        q += __shfl_xor(q, 1); q += __shfl_xor(q, 2);
        q += __shfl_xor(q, 4); q += __shfl_xor(q, 8);
        if (l16 == 0) {
          sSum[wvid * 64 + mt * 16 + lg * 4 + r] = s;
          sSq[wvid * 64 + mt * 16 + lg * 4 + r] = q;
        }
      }
    }
    __syncthreads();
    if (tid < 64) {
      float s = 0.f, q = 0.f;
#pragma unroll
      for (int w = 0; w < 8; ++w) { s += sSum[w * 64 + tid]; q += sSq[w * 64 + tid]; }
      float mean = s * (1.0f / 512.0f);
      float var = q * (1.0f / 512.0f) - mean * mean;
      sMean[tid] = mean;
      sRstd[tid] = rsqrtf(var + 1e-5f);
    }
    __syncthreads();
#pragma unroll
    for (int nt = 0; nt < 4; ++nt) {
      int col = ycol0 + nt * 16 + l16;
      float gv = g2[col], bv = beta2[col];
      float* op = ob + (size_t)col * 9216;
#pragma unroll
      for (int mt = 0; mt < 4; ++mt) {
        int tok0 = mt * 16 + lg * 4;
        float4 o4;
        o4.x = (Facc[mt][nt][0] - sMean[tok0 + 0]) * sRstd[tok0 + 0] * gv + bv;
        o4.y = (Facc[mt][nt][1] - sMean[tok0 + 1]) * sRstd[tok0 + 1] * gv + bv;
        o4.z = (Facc[mt][nt][2] - sMean[tok0 + 2]) * sRstd[tok0 + 2] * gv + bv;
        o4.w = (Facc[mt][nt][3] - sMean[tok0 + 3]) * sRstd[tok0 + 3] * gv + bv;
        *reinterpret_cast<float4*>(&op[(tok0 >> 3) * 96 + (tok0 & 7)]) = o4;
      }
    }
  }
}

extern "C" void kernel_launch(void* const* d_in, const int* in_sizes, int n_in,
                              void* d_out, int out_size, void* d_ws, size_t ws_size,
                              hipStream_t stream) {
  const float* x     = (const float*)d_in[0];
  const float* Wqkv  = (const float*)d_in[1];
  const float* bqkv  = (const float*)d_in[2];
  const float* Wo    = (const float*)d_in[3];
  const float* bo    = (const float*)d_in[4];
  const float* g1    = (const float*)d_in[5];
  const float* beta1 = (const float*)d_in[6];
  const float* W1    = (const float*)d_in[7];
  const float* bf1   = (const float*)d_in[8];
  const float* W2    = (const float*)d_in[9];
  const float* bf2   = (const float*)d_in[10];
  const float* g2    = (const float*)d_in[11];
  const float* beta2 = (const float*)d_in[12];
  float* out = (float*)d_out;

  unsigned short* ws = (unsigned short*)d_ws;
  unsigned short* WqkvT = ws;                          // 1536*512
  unsigned short* WoT   = ws + (size_t)1536 * 512;
  unsigned short* W1T   = WoT + (size_t)512 * 512;
  unsigned short* W2T   = W1T + (size_t)512 * 512;

  transpose_cvt_kernel<<<dim3(48, 16), 256, 0, stream>>>(Wqkv, WqkvT, 512, 1536);
  transpose_cvt_kernel<<<dim3(16, 16), 256, 0, stream>>>(Wo, WoT, 512, 512);
  transpose_cvt_kernel<<<dim3(16, 16), 256, 0, stream>>>(W1, W1T, 512, 512);
  transpose_cvt_kernel<<<dim3(16, 16), 256, 0, stream>>>(W2, W2T, 512, 512);

  (void)hipFuncSetAttribute((const void*)swin_fused,
                            hipFuncAttributeMaxDynamicSharedMemorySize, SMEM_BYTES);
  swin_fused<<<NWIN, 512, SMEM_BYTES, stream>>>(x, WqkvT, bqkv, WoT, bo, g1, beta1,
                                                W1T, bf1, W2T, bf2, g2, beta2, out);
}